// Round 13
// baseline (157.278 us; speedup 1.0000x reference)
//
#include <hip/hip_runtime.h>
#include <hip/hip_bf16.h>
#include <stdint.h>

typedef unsigned short u16;
typedef __bf16 bf16x8 __attribute__((ext_vector_type(8)));
typedef float f32x4 __attribute__((ext_vector_type(4)));

// ---------------- constants ----------------
// E=8, D=512, H=256, T=64, B=16384
// LDS (u16 units): A tile 64x512 = 32768 (64 KB), B chunk 128x64 = 8192 (16 KB)
#define LDS_B_OFF 32768

__device__ __forceinline__ void glds16(const void* g, void* l) {
  __builtin_amdgcn_global_load_lds(
      (const __attribute__((address_space(1))) unsigned int*)g,
      (__attribute__((address_space(3))) unsigned int*)l, 16, 0, 0);
}

__device__ __forceinline__ u16 f2bf(float f) {
  unsigned int u = __builtin_bit_cast(unsigned int, f);
  u += 0x7fffu + ((u >> 16) & 1u);   // round-to-nearest-even (finite inputs)
  return (u16)(u >> 16);
}

// ---------------- prep: weight conversion only ----------------
// bx 0..511: We -> We_bf; 512..519: Wt -> Wt_bf; 520..521: Wg -> hi/lo split
__global__ __launch_bounds__(256) void prep_w(
    const float* __restrict__ We, const float* __restrict__ Wt,
    const float* __restrict__ Wg,
    u16* __restrict__ We_bf, u16* __restrict__ Wt_bf,
    u16* __restrict__ Wg_hi, u16* __restrict__ Wg_lo) {
  const int bx = blockIdx.x;
  if (bx < 520) {
    const float* src; u16* dst;
    if (bx < 512) { int base = bx * 2048 + threadIdx.x * 8; src = We + base; dst = We_bf + base; }
    else { int base = (bx - 512) * 2048 + threadIdx.x * 8; src = Wt + base; dst = Wt_bf + base; }
    float4 a = *(const float4*)src;
    float4 b = *(const float4*)(src + 4);
    uint4 o;
    o.x = (unsigned)f2bf(a.x) | ((unsigned)f2bf(a.y) << 16);
    o.y = (unsigned)f2bf(a.z) | ((unsigned)f2bf(a.w) << 16);
    o.z = (unsigned)f2bf(b.x) | ((unsigned)f2bf(b.y) << 16);
    o.w = (unsigned)f2bf(b.z) | ((unsigned)f2bf(b.w) << 16);
    *(uint4*)dst = o;
  } else {
    int base = (bx - 520) * 2048 + threadIdx.x * 8;
    float x[8];
    float4 a = *(const float4*)(Wg + base);
    float4 b = *(const float4*)(Wg + base + 4);
    x[0]=a.x; x[1]=a.y; x[2]=a.z; x[3]=a.w; x[4]=b.x; x[5]=b.y; x[6]=b.z; x[7]=b.w;
    u16 h[8], l[8];
#pragma unroll
    for (int j = 0; j < 8; j++) {
      h[j] = f2bf(x[j]);
      float hf = __builtin_bit_cast(float, ((unsigned)h[j]) << 16);
      l[j] = f2bf(x[j] - hf);
    }
    uint4 oh, ol;
    oh.x = (unsigned)h[0] | ((unsigned)h[1] << 16);
    oh.y = (unsigned)h[2] | ((unsigned)h[3] << 16);
    oh.z = (unsigned)h[4] | ((unsigned)h[5] << 16);
    oh.w = (unsigned)h[6] | ((unsigned)h[7] << 16);
    ol.x = (unsigned)l[0] | ((unsigned)l[1] << 16);
    ol.y = (unsigned)l[2] | ((unsigned)l[3] << 16);
    ol.z = (unsigned)l[4] | ((unsigned)l[5] << 16);
    ol.w = (unsigned)l[6] | ((unsigned)l[7] << 16);
    *(uint4*)(Wg_hi + base) = oh;
    *(uint4*)(Wg_lo + base) = ol;
  }
}

// ---------------- main fused kernel ----------------
// r12 structure (XCD swizzle, BM=64, hb-half, 4 waves 2m x 2n, 2 blocks/CU,
// A-resident LDS, BK=64 B chunks) + FUSED xv prologue: each block converts
// its 64 xv rows f32->bf16 (A into LDS, wn==0 waves write) and computes the
// gate in-register via hi/lo-split bf16 MFMA + 8-lane softmax (r7-proven
// numerics, identical absmax). Kills prep's 4096-block xv pass (32 MB read
// + 16 MB write) and main's 16 MB xv_bf read; the hb-pair blocks share an
// XCD (swizzle maps orig o, o+1 to the same w%8) so xv is HBM-fetched ~once.
// XCD swizzle: orig = (w&7)<<6 | (w>>3); 512 % 8 == 0 -> bijective.
__global__ __launch_bounds__(256, 2) void moe_main(
    const float* __restrict__ xv, const u16* __restrict__ We_bf,
    const float* __restrict__ be, const float* __restrict__ bg,
    const u16* __restrict__ Wg_hi, const u16* __restrict__ Wg_lo,
    const u16* __restrict__ Wt_bf, float* __restrict__ part) {
  __shared__ u16 lds[40960];  // 80 KB: A[32768] + B[8192]

  const int bx = ((blockIdx.x & 7) << 6) | (blockIdx.x >> 3);  // XCD swizzle
  const int mb = bx >> 1;
  const int hb = bx & 1;
  const int m0 = mb << 6;
  const int tid = threadIdx.x;
  const int lane = tid & 63;
  const int wid = tid >> 6;
  const int wm = wid >> 1;  // 0..1 (row half)
  const int wn = wid & 1;   // 0..1 (col half)
  const int l15 = lane & 15;
  const int l4 = lane >> 4;  // 0..3

  // ---- fused prologue: xv f32 -> bf16 A-tile (LDS) + gate hi/lo MFMA ----
  // Each wave converts its wm-band's 32 rows (wn-pair duplicates the convert;
  // only wn==0 writes A). Gate logits accumulate in 3 chains; lane holds
  // logit[row = l4*4+i][e = l15&7].
  f32x4 g0[2] = {{0.f,0.f,0.f,0.f},{0.f,0.f,0.f,0.f}};
  f32x4 g1[2] = {{0.f,0.f,0.f,0.f},{0.f,0.f,0.f,0.f}};
  f32x4 g2[2] = {{0.f,0.f,0.f,0.f},{0.f,0.f,0.f,0.f}};
  const int esrc = l15 & 7;
#pragma unroll
  for (int mt = 0; mt < 2; mt++) {
#pragma unroll
    for (int ks = 0; ks < 16; ks++) {
      const int row = wm * 32 + mt * 16 + l15;
      const float* ap = xv + ((m0 + row) << 9) + ks * 32 + l4 * 8;
      float4 xa = *(const float4*)ap;
      float4 xb = *(const float4*)(ap + 4);
      float x[8];
      x[0]=xa.x; x[1]=xa.y; x[2]=xa.z; x[3]=xa.w; x[4]=xb.x; x[5]=xb.y; x[6]=xb.z; x[7]=xb.w;
      bf16x8 hv, lv;
#pragma unroll
      for (int j = 0; j < 8; j++) {
        u16 hb_ = f2bf(x[j]);
        float hf = __builtin_bit_cast(float, ((unsigned)hb_) << 16);
        hv[j] = __builtin_bit_cast(__bf16, hb_);
        lv[j] = __builtin_bit_cast(__bf16, f2bf(x[j] - hf));
      }
      if (wn == 0) {
        int gA = ks * 4 + l4;           // 0..63 k-granule
        int slotA = (gA & ~7) | ((gA & 7) ^ (row & 7));
        *(bf16x8*)&lds[(row << 9) + (slotA << 3)] = hv;
      }
      bf16x8 wh = *(const bf16x8*)(Wg_hi + (esrc << 9) + ks * 32 + l4 * 8);
      bf16x8 wl = *(const bf16x8*)(Wg_lo + (esrc << 9) + ks * 32 + l4 * 8);
      g0[mt] = __builtin_amdgcn_mfma_f32_16x16x32_bf16(hv, wh, g0[mt], 0, 0, 0);
      g1[mt] = __builtin_amdgcn_mfma_f32_16x16x32_bf16(lv, wh, g1[mt], 0, 0, 0);
      g2[mt] = __builtin_amdgcn_mfma_f32_16x16x32_bf16(hv, wl, g2[mt], 0, 0, 0);
    }
  }
  // softmax over experts (8-lane group reduce; lanes 8..15 duplicate)
  float gv[2][4];
  {
    float bgv = bg[esrc];
#pragma unroll
    for (int mt = 0; mt < 2; mt++)
#pragma unroll
      for (int i = 0; i < 4; i++) {
        float z = g0[mt][i] + g1[mt][i] + g2[mt][i] + bgv;
        float mx = z;
        mx = fmaxf(mx, __shfl_xor(mx, 1));
        mx = fmaxf(mx, __shfl_xor(mx, 2));
        mx = fmaxf(mx, __shfl_xor(mx, 4));
        float p = __expf(z - mx);
        float s = p;
        s += __shfl_xor(s, 1);
        s += __shfl_xor(s, 2);
        s += __shfl_xor(s, 4);
        gv[mt][i] = p / s;
      }
  }

  f32x4 comb[2][4];
#pragma unroll
  for (int mt = 0; mt < 2; mt++)
#pragma unroll
    for (int nt = 0; nt < 4; nt++) comb[mt][nt] = {0.f, 0.f, 0.f, 0.f};

  for (int e = 0; e < 8; e++) {
    f32x4 acc[2][4];
#pragma unroll
    for (int mt = 0; mt < 2; mt++)
#pragma unroll
      for (int nt = 0; nt < 4; nt++) acc[mt][nt] = {0.f, 0.f, 0.f, 0.f};

    const u16* Wb = We_bf + (e << 17) + (hb << 16);  // this e, this h-half
    for (int kc = 0; kc < 8; kc++) {
      __syncthreads();                // readers of previous B chunk done
      // stage B: 128 rows x 64 k (1024 granules, 4/thread); row n slot s
      // holds source granule g = s ^ (n&7)
#pragma unroll
      for (int r = 0; r < 4; r++) {
        int gi = r * 256 + tid;       // 0..1023
        int n = gi >> 3, s = gi & 7;
        int g = s ^ (n & 7);
        glds16(Wb + (n << 9) + (kc << 6) + (g << 3), &lds[LDS_B_OFF + (gi << 3)]);
      }
      __syncthreads();                // B chunk (and, first pass, A) visible
#pragma unroll
      for (int ks = 0; ks < 2; ks++) {
        bf16x8 af[2], bfr[4];
#pragma unroll
        for (int mt = 0; mt < 2; mt++) {
          int row = wm * 32 + mt * 16 + l15;
          int gk = kc * 8 + ks * 4 + l4;          // 0..63 global A granule
          int slot = (gk & ~7) | ((gk & 7) ^ (row & 7));
          af[mt] = *(const bf16x8*)&lds[(row << 9) + (slot << 3)];
        }
#pragma unroll
        for (int nt = 0; nt < 4; nt++) {
          int n = wn * 64 + nt * 16 + l15;
          int gB = ks * 4 + l4;                   // 0..7 chunk granule
          int slot = gB ^ (n & 7);
          bfr[nt] = *(const bf16x8*)&lds[LDS_B_OFF + (n << 6) + (slot << 3)];
        }
#pragma unroll
        for (int mt = 0; mt < 2; mt++)
#pragma unroll
          for (int nt = 0; nt < 4; nt++)
            acc[mt][nt] = __builtin_amdgcn_mfma_f32_16x16x32_bf16(
                af[mt], bfr[nt], acc[mt][nt], 0, 0, 0);
      }
    }
    // fold: comb += gate[m,e] * relu(acc + be[e,h]); gate from regs via shfl
    float bev[4];
#pragma unroll
    for (int nt = 0; nt < 4; nt++)
      bev[nt] = be[(e << 8) + (hb << 7) + wn * 64 + nt * 16 + l15];
#pragma unroll
    for (int mt = 0; mt < 2; mt++) {
#pragma unroll
      for (int i = 0; i < 4; i++) {
        float g = __shfl(gv[mt][i], (lane & 48) | e);
#pragma unroll
        for (int nt = 0; nt < 4; nt++)
          comb[mt][nt][i] += g * fmaxf(acc[mt][nt][i] + bev[nt], 0.f);
      }
    }
  }

  // ---- tower partial: out_part[m, t] = sum_{h in this half} comb[m,h]*Wt[t,h]
  __syncthreads();                    // all waves done reading A/B regions
  // write comb to LDS as bf16, [64][136] (pad +8 elems = 16B, keeps alignment)
#pragma unroll
  for (int mt = 0; mt < 2; mt++)
#pragma unroll
    for (int i = 0; i < 4; i++) {
      int row = wm * 32 + mt * 16 + l4 * 4 + i;
#pragma unroll
      for (int nt = 0; nt < 4; nt++) {
        int col = wn * 64 + nt * 16 + l15;
        __bf16 v = (__bf16)comb[mt][nt][i];
        lds[row * 136 + col] = __builtin_bit_cast(u16, v);
      }
    }
  __syncthreads();
  f32x4 tacc[4];
#pragma unroll
  for (int nt = 0; nt < 4; nt++) tacc[nt] = {0.f, 0.f, 0.f, 0.f};
  const u16* WtB = Wt_bf + (hb << 7);
#pragma unroll
  for (int kc = 0; kc < 4; kc++) {
    int ko = kc * 32 + l4 * 8;
    bf16x8 aT = *(const bf16x8*)&lds[(wid * 16 + l15) * 136 + ko];
#pragma unroll
    for (int nt = 0; nt < 4; nt++) {
      bf16x8 bT = *(const bf16x8*)&WtB[(nt * 16 + l15) * 256 + ko];
      tacc[nt] = __builtin_amdgcn_mfma_f32_16x16x32_bf16(aT, bT, tacc[nt], 0, 0, 0);
    }
  }
  float* pout = part + hb * 1048576;
#pragma unroll
  for (int nt = 0; nt < 4; nt++)
#pragma unroll
    for (int i = 0; i < 4; i++) {
      int grow = m0 + wid * 16 + l4 * 4 + i;
      pout[grow * 64 + nt * 16 + l15] = tacc[nt][i];
    }
}

// ---------------- finish: sigmoid(part0 + part1 + bt) ----------------
__global__ __launch_bounds__(256) void finish_kernel(
    const float* __restrict__ part, const float* __restrict__ bt,
    float* __restrict__ out) {
  const int idx = (blockIdx.x * 256 + threadIdx.x) << 2;
  float4 a = *(const float4*)(part + idx);
  float4 b = *(const float4*)(part + 1048576 + idx);
  float4 c = *(const float4*)(bt + (idx & 63));
  float4 r;
  r.x = 1.f / (1.f + __expf(-(a.x + b.x + c.x)));
  r.y = 1.f / (1.f + __expf(-(a.y + b.y + c.y)));
  r.z = 1.f / (1.f + __expf(-(a.z + b.z + c.z)));
  r.w = 1.f / (1.f + __expf(-(a.w + b.w + c.w)));
  *(float4*)(out + idx) = r;
}

extern "C" void kernel_launch(void* const* d_in, const int* in_sizes, int n_in,
                              void* d_out, int out_size, void* d_ws, size_t ws_size,
                              hipStream_t stream) {
  const float* xv = (const float*)d_in[0];
  const float* We = (const float*)d_in[1];
  const float* be = (const float*)d_in[2];
  const float* Wg = (const float*)d_in[3];
  const float* bg = (const float*)d_in[4];
  const float* Wt = (const float*)d_in[5];
  const float* bt = (const float*)d_in[6];

  char* ws = (char*)d_ws;
  u16* We_bf = (u16*)ws;                        // 2 MB   (8*256*512 bf16)
  u16* Wt_bf = (u16*)(ws + 2097152);            // 32 KB  (64*256 bf16)
  u16* Wg_hi = (u16*)(ws + 2129920);            // 8 KB   (8*512 bf16)
  u16* Wg_lo = (u16*)(ws + 2138112);            // 8 KB
  float* part = (float*)(ws + 2146304);         // 8 MB   (2*16384*64 f32)

  prep_w<<<522, 256, 0, stream>>>(We, Wt, Wg, We_bf, Wt_bf, Wg_hi, Wg_lo);
  moe_main<<<512, 256, 0, stream>>>(xv, We_bf, be, bg, Wg_hi, Wg_lo, Wt_bf, part);
  finish_kernel<<<1024, 256, 0, stream>>>(part, bt, (float*)d_out);
}

// Round 14
// 142.877 us; speedup vs baseline: 1.1008x; 1.1008x over previous
//
#include <hip/hip_runtime.h>
#include <hip/hip_bf16.h>
#include <stdint.h>

typedef unsigned short u16;
typedef __bf16 bf16x8 __attribute__((ext_vector_type(8)));
typedef float f32x4 __attribute__((ext_vector_type(4)));

// ---------------- constants ----------------
// E=8, D=512, H=256, T=64, B=16384
// LDS (u16 units): A tile 64x512 = 32768 (64 KB) + 2 B-chunk bufs of
// 128 rows x 32 k = 4096 u16 (8 KB) each -> 80 KB total, 2 blocks/CU.
#define LDS_B_OFF 32768

__device__ __forceinline__ void glds16(const void* g, void* l) {
  __builtin_amdgcn_global_load_lds(
      (const __attribute__((address_space(1))) unsigned int*)g,
      (__attribute__((address_space(3))) unsigned int*)l, 16, 0, 0);
}

__device__ __forceinline__ u16 f2bf(float f) {
  unsigned int u = __builtin_bit_cast(unsigned int, f);
  u += 0x7fffu + ((u >> 16) & 1u);   // round-to-nearest-even (finite inputs)
  return (u16)(u >> 16);
}

// ---------------- prep: bf16 conversion + gate softmax ----------------
// blocks 0..4095: 4 rows each (one wave per row): convert xv row + gate softmax
// blocks 4096..4615: convert We (512 blocks) then Wt (8 blocks), 2048 elems each
__global__ __launch_bounds__(256) void prep_kernel(
    const float* __restrict__ xv, const float* __restrict__ We,
    const float* __restrict__ Wg, const float* __restrict__ bg,
    const float* __restrict__ Wt,
    u16* __restrict__ xv_bf, u16* __restrict__ We_bf,
    u16* __restrict__ Wt_bf, float* __restrict__ gate) {
  const int bx = blockIdx.x;
  if (bx < 4096) {
    const int wid = threadIdx.x >> 6, lane = threadIdx.x & 63;
    const int row = bx * 4 + wid;
    const float* xr = xv + (row << 9) + lane * 8;
    float4 x0 = *(const float4*)xr;
    float4 x1 = *(const float4*)(xr + 4);
    uint4 o;
    o.x = (unsigned)f2bf(x0.x) | ((unsigned)f2bf(x0.y) << 16);
    o.y = (unsigned)f2bf(x0.z) | ((unsigned)f2bf(x0.w) << 16);
    o.z = (unsigned)f2bf(x1.x) | ((unsigned)f2bf(x1.y) << 16);
    o.w = (unsigned)f2bf(x1.z) | ((unsigned)f2bf(x1.w) << 16);
    *(uint4*)(xv_bf + (row << 9) + lane * 8) = o;
    // gate logits
    float s[8];
#pragma unroll
    for (int e = 0; e < 8; e++) {
      const float* wg = Wg + (e << 9) + lane * 8;
      float4 w0 = *(const float4*)wg;
      float4 w1 = *(const float4*)(wg + 4);
      s[e] = x0.x * w0.x + x0.y * w0.y + x0.z * w0.z + x0.w * w0.w +
             x1.x * w1.x + x1.y * w1.y + x1.z * w1.z + x1.w * w1.w;
    }
#pragma unroll
    for (int e = 0; e < 8; e++) {
#pragma unroll
      for (int off = 32; off > 0; off >>= 1) s[e] += __shfl_xor(s[e], off);
      s[e] += bg[e];
    }
    float mx = s[0];
#pragma unroll
    for (int e = 1; e < 8; e++) mx = fmaxf(mx, s[e]);
    float p[8], sum = 0.f;
#pragma unroll
    for (int e = 0; e < 8; e++) { p[e] = __expf(s[e] - mx); sum += p[e]; }
    float inv = 1.f / sum;
    if (lane == 0) {
      float4 g0 = {p[0] * inv, p[1] * inv, p[2] * inv, p[3] * inv};
      float4 g1 = {p[4] * inv, p[5] * inv, p[6] * inv, p[7] * inv};
      *(float4*)(gate + row * 8) = g0;
      *(float4*)(gate + row * 8 + 4) = g1;
    }
  } else {
    const int base = (bx - 4096) * 2048 + threadIdx.x * 8;
    const float* src;
    u16* dst;
    if (base < 1048576) { src = We + base; dst = We_bf + base; }
    else { src = Wt + (base - 1048576); dst = Wt_bf + (base - 1048576); }
    float4 a = *(const float4*)src;
    float4 b = *(const float4*)(src + 4);
    uint4 o;
    o.x = (unsigned)f2bf(a.x) | ((unsigned)f2bf(a.y) << 16);
    o.y = (unsigned)f2bf(a.z) | ((unsigned)f2bf(a.w) << 16);
    o.z = (unsigned)f2bf(b.x) | ((unsigned)f2bf(b.y) << 16);
    o.w = (unsigned)f2bf(b.z) | ((unsigned)f2bf(b.w) << 16);
    *(uint4*)dst = o;
  }
}

// ---------------- main fused kernel ----------------
// r12 frame (XCD swizzle, BM=64, hb-half, 4 waves 2m x 2n, 2 blocks/CU,
// A-resident LDS) with the m97-canonical SINGLE-BARRIER DOUBLE-BUFFERED
// B stream: per phase {stage chunk t+1 into buf[(t+1)&1] -> compute chunk t
// from buf[t&1] -> __syncthreads()}. The implicit vmcnt(0) drain at the
// barrier retires chunk t+1's loads, which flew UNDER the compute — r12's
// bar->stage->bar->compute exposed the full L2 latency between barriers.
// Plain __syncthreads only (no manual vmcnt counting -> r6's race class is
// impossible by construction). BK=32: chunk = 128x32 = 8 KB; 2 bufs + A =
// exactly 80 KB -> 2 blocks/CU preserved. Barrier count unchanged (128x1
// vs r12's 64x2).
// B swizzle re-derived for 4-granule rows: stage src g = s^(n&3), reader
// slot = l4^(n&3) (involution; reads spread over 8 bank-bases).
// XCD swizzle: orig = (w&7)<<6 | (w>>3); 512 % 8 == 0 -> bijective.
__global__ __launch_bounds__(256, 2) void moe_main(
    const u16* __restrict__ xv_bf, const u16* __restrict__ We_bf,
    const float* __restrict__ be, const float* __restrict__ gate,
    const u16* __restrict__ Wt_bf, float* __restrict__ part) {
  __shared__ u16 lds[40960];  // 80 KB: A[32768] + B0[4096] + B1[4096]

  const int bx = ((blockIdx.x & 7) << 6) | (blockIdx.x >> 3);  // XCD swizzle
  const int mb = bx >> 1;
  const int hb = bx & 1;
  const int m0 = mb << 6;
  const int tid = threadIdx.x;
  const int lane = tid & 63;
  const int wid = tid >> 6;
  const int wm = wid >> 1;  // 0..1 (row half)
  const int wn = wid & 1;   // 0..1 (col half)
  const int l15 = lane & 15;
  const int l4 = lane >> 4;  // 0..3

  // ---- prologue: stage full A tile (16/thread) + B chunk 0 (2/thread) ----
  // A row r, k-granule s (0..63): LDS slot s holds source granule
  // g = (s&~7) | ((s&7)^(r&7)); reader inverts with the same formula.
#pragma unroll
  for (int r = 0; r < 16; r++) {
    int gi = r * 256 + tid;           // 0..4095
    int m = gi >> 6, s = gi & 63;
    int g = (s & ~7) | ((s & 7) ^ (m & 7));
    glds16(xv_bf + ((m0 + m) << 9) + (g << 3), &lds[gi << 3]);
  }
  {
    const u16* Wb0 = We_bf + (hb << 16);
#pragma unroll
    for (int r = 0; r < 2; r++) {
      int gi = r * 256 + tid;         // 0..511
      int n = gi >> 2, s = gi & 3;
      int g = s ^ (n & 3);
      glds16(Wb0 + (n << 9) + (g << 3), &lds[LDS_B_OFF + (gi << 3)]);
    }
  }
  __syncthreads();                    // A + chunk0 resident

  f32x4 comb[2][4];
#pragma unroll
  for (int mt = 0; mt < 2; mt++)
#pragma unroll
    for (int nt = 0; nt < 4; nt++) comb[mt][nt] = {0.f, 0.f, 0.f, 0.f};

  for (int e = 0; e < 8; e++) {
    f32x4 acc[2][4];
#pragma unroll
    for (int mt = 0; mt < 2; mt++)
#pragma unroll
      for (int nt = 0; nt < 4; nt++) acc[mt][nt] = {0.f, 0.f, 0.f, 0.f};

#pragma unroll
    for (int kk = 0; kk < 16; kk++) {  // chunk t = e*16+kk; buf = kk&1
      const int t = e * 16 + kk;
      // stage next chunk (flies under this phase's compute)
      if (t < 127) {
        const int tn = t + 1;
        const u16* Wbn = We_bf + ((tn >> 4) << 17) + (hb << 16) + ((tn & 15) << 5);
#pragma unroll
        for (int r = 0; r < 2; r++) {
          int gi = r * 256 + tid;
          int n = gi >> 2, s = gi & 3;
          int g = s ^ (n & 3);
          glds16(Wbn + (n << 9) + (g << 3),
                 &lds[LDS_B_OFF + ((tn & 1) << 12) + (gi << 3)]);
        }
      }
      // compute chunk t
      const u16* Bb = &lds[LDS_B_OFF + ((t & 1) << 12)];
      bf16x8 af[2], bfr[4];
#pragma unroll
      for (int mt = 0; mt < 2; mt++) {
        int row = wm * 32 + mt * 16 + l15;
        int gA = kk * 4 + l4;                     // 0..63 global A granule
        int slot = (gA & ~7) | ((gA & 7) ^ (row & 7));
        af[mt] = *(const bf16x8*)&lds[(row << 9) + (slot << 3)];
      }
#pragma unroll
      for (int nt = 0; nt < 4; nt++) {
        int n = wn * 64 + nt * 16 + l15;
        int slot = l4 ^ (n & 3);                  // 4-granule row swizzle
        bfr[nt] = *(const bf16x8*)&Bb[(n << 5) + (slot << 3)];
      }
#pragma unroll
      for (int mt = 0; mt < 2; mt++)
#pragma unroll
        for (int nt = 0; nt < 4; nt++)
          acc[mt][nt] = __builtin_amdgcn_mfma_f32_16x16x32_bf16(
              af[mt], bfr[nt], acc[mt][nt], 0, 0, 0);
      __syncthreads();                // next chunk landed; buf[t&1] readers done
    }
    // fold: comb += gate[m,e] * relu(acc + be[e,h])
    float bev[4];
#pragma unroll
    for (int nt = 0; nt < 4; nt++)
      bev[nt] = be[(e << 8) + (hb << 7) + wn * 64 + nt * 16 + l15];
#pragma unroll
    for (int mt = 0; mt < 2; mt++) {
#pragma unroll
      for (int i = 0; i < 4; i++) {
        float g = gate[((m0 + wm * 32 + mt * 16 + l4 * 4 + i) << 3) + e];
#pragma unroll
        for (int nt = 0; nt < 4; nt++)
          comb[mt][nt][i] += g * fmaxf(acc[mt][nt][i] + bev[nt], 0.f);
      }
    }
  }

  // ---- tower partial: out_part[m, t] = sum_{h in this half} comb[m,h]*Wt[t,h]
  __syncthreads();                    // (redundant w/ last phase barrier; cheap)
  // write comb to LDS as bf16, [64][136] (pad +8 elems = 16B, keeps alignment)
#pragma unroll
  for (int mt = 0; mt < 2; mt++)
#pragma unroll
    for (int i = 0; i < 4; i++) {
      int row = wm * 32 + mt * 16 + l4 * 4 + i;
#pragma unroll
      for (int nt = 0; nt < 4; nt++) {
        int col = wn * 64 + nt * 16 + l15;
        __bf16 v = (__bf16)comb[mt][nt][i];
        lds[row * 136 + col] = __builtin_bit_cast(u16, v);
      }
    }
  __syncthreads();
  f32x4 tacc[4];
#pragma unroll
  for (int nt = 0; nt < 4; nt++) tacc[nt] = {0.f, 0.f, 0.f, 0.f};
  const u16* WtB = Wt_bf + (hb << 7);
#pragma unroll
  for (int kc = 0; kc < 4; kc++) {
    int ko = kc * 32 + l4 * 8;
    bf16x8 aT = *(const bf16x8*)&lds[(wid * 16 + l15) * 136 + ko];
#pragma unroll
    for (int nt = 0; nt < 4; nt++) {
      bf16x8 bT = *(const bf16x8*)&WtB[(nt * 16 + l15) * 256 + ko];
      tacc[nt] = __builtin_amdgcn_mfma_f32_16x16x32_bf16(aT, bT, tacc[nt], 0, 0, 0);
    }
  }
  float* pout = part + hb * 1048576;
#pragma unroll
  for (int nt = 0; nt < 4; nt++)
#pragma unroll
    for (int i = 0; i < 4; i++) {
      int grow = m0 + wid * 16 + l4 * 4 + i;
      pout[grow * 64 + nt * 16 + l15] = tacc[nt][i];
    }
}

// ---------------- finish: sigmoid(part0 + part1 + bt) ----------------
__global__ __launch_bounds__(256) void finish_kernel(
    const float* __restrict__ part, const float* __restrict__ bt,
    float* __restrict__ out) {
  const int idx = (blockIdx.x * 256 + threadIdx.x) << 2;
  float4 a = *(const float4*)(part + idx);
  float4 b = *(const float4*)(part + 1048576 + idx);
  float4 c = *(const float4*)(bt + (idx & 63));
  float4 r;
  r.x = 1.f / (1.f + __expf(-(a.x + b.x + c.x)));
  r.y = 1.f / (1.f + __expf(-(a.y + b.y + c.y)));
  r.z = 1.f / (1.f + __expf(-(a.z + b.z + c.z)));
  r.w = 1.f / (1.f + __expf(-(a.w + b.w + c.w)));
  *(float4*)(out + idx) = r;
}

extern "C" void kernel_launch(void* const* d_in, const int* in_sizes, int n_in,
                              void* d_out, int out_size, void* d_ws, size_t ws_size,
                              hipStream_t stream) {
  const float* xv = (const float*)d_in[0];
  const float* We = (const float*)d_in[1];
  const float* be = (const float*)d_in[2];
  const float* Wg = (const float*)d_in[3];
  const float* bg = (const float*)d_in[4];
  const float* Wt = (const float*)d_in[5];
  const float* bt = (const float*)d_in[6];

  char* ws = (char*)d_ws;
  u16* xv_bf = (u16*)ws;                      // 16 MB  (16384*512 bf16)
  u16* We_bf = (u16*)(ws + 16777216);         // 2 MB   (2048*512 bf16)
  u16* Wt_bf = (u16*)(ws + 18874368);         // 32 KB  (64*256 bf16)
  float* gate = (float*)(ws + 18907136);      // 512 KB (16384*8 f32)
  float* part = (float*)(ws + 19431424);      // 8 MB   (2*16384*64 f32)

  prep_kernel<<<4616, 256, 0, stream>>>(xv, We, Wg, bg, Wt, xv_bf, We_bf, Wt_bf, gate);
  moe_main<<<512, 256, 0, stream>>>(xv_bf, We_bf, be, gate, Wt_bf, part);
  finish_kernel<<<1024, 256, 0, stream>>>(part, bt, (float*)d_out);
}